// Round 5
// baseline (877.777 us; speedup 1.0000x reference)
//
#include <hip/hip_runtime.h>
#include <hip/hip_cooperative_groups.h>

namespace cg = cooperative_groups;

// Problem constants derived at launch from in_sizes:
// in[0]=x [B,TF,T], in[1]=gene_ids [T], in[2]=w_sub [TF,T], in[3]=b_sub [G],
// in[4]=edge_index [2,2E], in[5]=w_conv [1,2], in[6]=b_conv [2],
// in[7]=w_out [2G,3], in[8]=b_out [3]
// d_out = x_cat [B,G] ++ g [B,2G] ++ out [B,3]  (float32)

typedef float f32x4 __attribute__((ext_vector_type(4)));

// ---------------- Stage 1: per-gene subnet dot + segment scatter ----------------
// EXACT R1 form (723 us total): 4 cols/thread, 16B coalesced lane loads, 2-D grid.
// R3 (8-wide: broke coalescing, +19us) and R4 (XCD swizzle: null) both reverted.
__global__ void k_subnet(const float* __restrict__ x, const float* __restrict__ w_sub,
                         const int* __restrict__ gene_ids, float* __restrict__ acc,
                         int TF, int T, int G) {
    int t = (blockIdx.x * blockDim.x + threadIdx.x) * 4;
    int b = blockIdx.y;
    if (t >= T) return;
    const size_t xbase = (size_t)b * TF * T;
    if (t + 3 < T && (T % 4) == 0) {
        const f32x4* xp = (const f32x4*)(x + xbase + t);
        const f32x4* wp = (const f32x4*)(w_sub + t);
        const size_t strideV = (size_t)T / 4;
        f32x4 a = {0.f, 0.f, 0.f, 0.f};
        #pragma unroll 8
        for (int tf = 0; tf < TF; ++tf) {
            f32x4 xv = __builtin_nontemporal_load(xp + (size_t)tf * strideV);
            f32x4 wv = wp[(size_t)tf * strideV];
            a += xv * wv;
        }
        int4 gi = *(const int4*)(gene_ids + t);
        float* base = acc + (size_t)b * G;
        // merge adjacent columns belonging to the same gene before atomics
        float v = a.x; int cg = gi.x;
        if (gi.y == cg) v += a.y; else { atomicAdd(base + cg, v); cg = gi.y; v = a.y; }
        if (gi.z == cg) v += a.z; else { atomicAdd(base + cg, v); cg = gi.z; v = a.z; }
        if (gi.w == cg) v += a.w; else { atomicAdd(base + cg, v); cg = gi.w; v = a.w; }
        atomicAdd(base + cg, v);
    } else {
        // scalar tail (not taken for T % 4 == 0, kept for generality)
        for (int tt = t; tt < T && tt < t + 4; ++tt) {
            float a = 0.f;
            for (int tf = 0; tf < TF; ++tf)
                a += x[xbase + (size_t)tf * T + tt] * w_sub[(size_t)tf * T + tt];
            atomicAdd(acc + (size_t)b * G + gene_ids[tt], a);
        }
    }
}

// ============ Stages 2-4 fused into ONE small cooperative kernel ============
// Phase code identical to the verified R2 mega-kernel phases (which PASSED);
// R2's slowness was the subnet phase's VGPR clamp, not these. 512 blocks x 256
// (2 blocks/CU — trivially co-resident, no __launch_bounds__, natural VGPRs).
//   PA: zero deg[G], s[BG]; out_fin = bias
//   PB: xcat = relu(acc + b_sub); deg histogram
//   PC: edge scatter with on-the-fly GCN norm (edge-loop over b)
//   PD: g = relu(w_conv*s + b_conv); out += g @ w_out (wave-reduce + atomics)
__global__ void k_tail(const float* __restrict__ acc, const float* __restrict__ b_sub,
                       float* __restrict__ xcat,
                       const int* __restrict__ ei, float* __restrict__ deg,
                       float* __restrict__ s,
                       const float* __restrict__ w_conv, const float* __restrict__ b_conv,
                       const float* __restrict__ w_out, const float* __restrict__ b_out,
                       float* __restrict__ out_g, float* __restrict__ out_fin,
                       int B, int G, int E2) {
    cg::grid_group gg = cg::this_grid();
    const int tid = blockIdx.x * blockDim.x + threadIdx.x;
    const int nth = gridDim.x * blockDim.x;
    const int BG = B * G;

    // PA
    for (int i = tid; i < G; i += nth) deg[i] = 0.f;
    for (int i = tid; i < BG; i += nth) s[i] = 0.f;
    if (tid < B * 3) out_fin[tid] = b_out[tid % 3];
    gg.sync();

    // PB
    for (int i = tid; i < BG; i += nth) {
        int g = i % G;
        float v = acc[i] + b_sub[g];
        xcat[i] = v > 0.f ? v : 0.f;
    }
    for (int e = tid; e < E2; e += nth) atomicAdd(&deg[ei[E2 + e]], 1.0f);
    gg.sync();

    // PC
    for (int e = tid; e < E2; e += nth) {
        int src = ei[e], dst = ei[E2 + e];
        float ds = deg[src], dd = deg[dst];
        float ns = (ds > 0.f) ? (1.0f / sqrtf(fmaxf(ds, 1.0f))) : 0.f;
        float nd = (dd > 0.f) ? (1.0f / sqrtf(fmaxf(dd, 1.0f))) : 0.f;
        float norm = ns * nd;
        for (int b = 0; b < B; ++b)
            atomicAdd(&s[(size_t)b * G + dst], xcat[(size_t)b * G + src] * norm);
    }
    gg.sync();

    // PD
    {
        const float wc0 = w_conv[0], wc1 = w_conv[1];
        const float bc0 = b_conv[0], bc1 = b_conv[1];
        const int wid = tid >> 6, lane = tid & 63;
        const int WPB = (G + 63) >> 6;          // waves per batch row
        if (wid < B * WPB) {
            int b = wid / WPB;
            int n = (wid - b * WPB) * 64 + lane;
            float a0 = 0.f, a1 = 0.f, a2 = 0.f;
            if (n < G) {
                size_t i = (size_t)b * G + n;
                float sv = s[i];
                float g0 = fmaxf(sv * wc0 + bc0, 0.f);
                float g1 = fmaxf(sv * wc1 + bc1, 0.f);
                out_g[2 * i + 0] = g0;          // b*2G + 2n + f == 2*i + f
                out_g[2 * i + 1] = g1;
                const float* w0 = w_out + (size_t)6 * n;   // rows 2n, 2n+1 of [2G,3]
                a0 = g0 * w0[0] + g1 * w0[3];
                a1 = g0 * w0[1] + g1 * w0[4];
                a2 = g0 * w0[2] + g1 * w0[5];
            }
            for (int off = 32; off > 0; off >>= 1) {
                a0 += __shfl_down(a0, off);
                a1 += __shfl_down(a1, off);
                a2 += __shfl_down(a2, off);
            }
            if (lane == 0) {
                atomicAdd(&out_fin[b * 3 + 0], a0);
                atomicAdd(&out_fin[b * 3 + 1], a1);
                atomicAdd(&out_fin[b * 3 + 2], a2);
            }
        }
    }
}

// ==================== Fallback path (proven R1 kernels) ====================
__global__ void k_xcatdeg(const float* __restrict__ acc, const float* __restrict__ b_sub,
                          float* __restrict__ xcat,
                          const int* __restrict__ ei, float* __restrict__ deg,
                          const float* __restrict__ b_out, float* __restrict__ out_fin,
                          int BG, int G, int E2, int B3) {
    int i = blockIdx.x * blockDim.x + threadIdx.x;
    if (i < BG) {
        int g = i % G;
        float v = acc[i] + b_sub[g];
        xcat[i] = v > 0.f ? v : 0.f;
    }
    if (i < E2) atomicAdd(&deg[ei[E2 + i]], 1.0f);
    if (i < B3) out_fin[i] = b_out[i % 3];
}

__global__ void k_scatter(const float* __restrict__ xcat, const int* __restrict__ ei,
                          const float* __restrict__ deg, float* __restrict__ s,
                          int G, int E2) {
    int e = blockIdx.x * blockDim.x + threadIdx.x;
    if (e >= E2) return;
    int b = blockIdx.y;
    int src = ei[e], dst = ei[E2 + e];
    float ds = deg[src], dd = deg[dst];
    float ns = (ds > 0.f) ? (1.0f / sqrtf(fmaxf(ds, 1.0f))) : 0.f;
    float nd = (dd > 0.f) ? (1.0f / sqrtf(fmaxf(dd, 1.0f))) : 0.f;
    atomicAdd(&s[(size_t)b * G + dst], xcat[(size_t)b * G + src] * (ns * nd));
}

__global__ void k_gfinout(const float* __restrict__ s, const float* __restrict__ w_conv,
                          const float* __restrict__ b_conv, const float* __restrict__ w_out,
                          float* __restrict__ gout, float* __restrict__ out_fin, int G) {
    int n = blockIdx.x * blockDim.x + threadIdx.x;
    int b = blockIdx.y;
    float a0 = 0.f, a1 = 0.f, a2 = 0.f;
    if (n < G) {
        size_t i = (size_t)b * G + n;
        float sv = s[i];
        float g0 = sv * w_conv[0] + b_conv[0]; g0 = g0 > 0.f ? g0 : 0.f;
        float g1 = sv * w_conv[1] + b_conv[1]; g1 = g1 > 0.f ? g1 : 0.f;
        gout[2 * i + 0] = g0;
        gout[2 * i + 1] = g1;
        const float* w0 = w_out + (size_t)6 * n;
        a0 = g0 * w0[0] + g1 * w0[3];
        a1 = g0 * w0[1] + g1 * w0[4];
        a2 = g0 * w0[2] + g1 * w0[5];
    }
    for (int off = 32; off > 0; off >>= 1) {
        a0 += __shfl_down(a0, off);
        a1 += __shfl_down(a1, off);
        a2 += __shfl_down(a2, off);
    }
    __shared__ float red[3][4];
    int lane = threadIdx.x & 63;
    int wid  = threadIdx.x >> 6;
    if (lane == 0) { red[0][wid] = a0; red[1][wid] = a1; red[2][wid] = a2; }
    __syncthreads();
    if (threadIdx.x == 0) {
        atomicAdd(&out_fin[b * 3 + 0], red[0][0] + red[0][1] + red[0][2] + red[0][3]);
        atomicAdd(&out_fin[b * 3 + 1], red[1][0] + red[1][1] + red[1][2] + red[1][3]);
        atomicAdd(&out_fin[b * 3 + 2], red[2][0] + red[2][1] + red[2][2] + red[2][3]);
    }
}

extern "C" void kernel_launch(void* const* d_in, const int* in_sizes, int n_in,
                              void* d_out, int out_size, void* d_ws, size_t ws_size,
                              hipStream_t stream) {
    const float* x        = (const float*)d_in[0];
    const int*   gene_ids = (const int*)d_in[1];
    const float* w_sub    = (const float*)d_in[2];
    const float* b_sub    = (const float*)d_in[3];
    const int*   ei       = (const int*)d_in[4];
    const float* w_conv   = (const float*)d_in[5];
    const float* b_conv   = (const float*)d_in[6];
    const float* w_out    = (const float*)d_in[7];
    const float* b_out    = (const float*)d_in[8];

    int G  = in_sizes[3];
    int T  = in_sizes[1];
    int TF = in_sizes[2] / T;
    int B  = in_sizes[0] / (TF * T);
    int E2 = in_sizes[4] / 2;     // 2E
    const int BG = B * G;

    // workspace layout (floats): acc[BG] | deg[G] | s[BG]
    float* acc = (float*)d_ws;
    float* deg = acc + BG;
    float* s   = deg + G;

    float* out_xcat = (float*)d_out;            // [B, G]
    float* out_g    = out_xcat + BG;            // [B, 2G]
    float* out_fin  = out_g + (size_t)2 * BG;   // [B, 3]

    // acc must be zero before k_subnet; deg/s are zeroed inside k_tail.
    hipMemsetAsync(acc, 0, (size_t)BG * sizeof(float), stream);

    // Stage 1 (exact R1 launch)
    {
        int tthreads = (T + 3) / 4;
        dim3 grid((tthreads + 255) / 256, B);
        k_subnet<<<grid, 256, 0, stream>>>(x, w_sub, gene_ids, acc, TF, T, G);
    }

    // Stages 2-4: one cooperative kernel (512 blocks x 256)
    void* args[] = {
        (void*)&acc, (void*)&b_sub, (void*)&out_xcat, (void*)&ei, (void*)&deg,
        (void*)&s, (void*)&w_conv, (void*)&b_conv, (void*)&w_out, (void*)&b_out,
        (void*)&out_g, (void*)&out_fin, (void*)&B, (void*)&G, (void*)&E2
    };
    hipError_t err = hipLaunchCooperativeKernel((const void*)k_tail, dim3(512), dim3(256),
                                                args, 0, stream);
    if (err == hipSuccess) return;

    // ---- fallback: proven R1 multi-dispatch tail ----
    hipMemsetAsync(deg, 0, (size_t)(G + BG) * sizeof(float), stream);
    {
        int mx = BG > E2 ? BG : E2;
        int b3 = B * 3;
        if (mx < b3) mx = b3;
        k_xcatdeg<<<(mx + 255) / 256, 256, 0, stream>>>(acc, b_sub, out_xcat, ei, deg,
                                                        b_out, out_fin, BG, G, E2, b3);
    }
    {
        dim3 grid((E2 + 255) / 256, B);
        k_scatter<<<grid, 256, 0, stream>>>(out_xcat, ei, deg, s, G, E2);
    }
    {
        dim3 grid((G + 255) / 256, B);
        k_gfinout<<<grid, 256, 0, stream>>>(s, w_conv, b_conv, w_out, out_g, out_fin, G);
    }
}

// Round 6
// 722.024 us; speedup vs baseline: 1.2157x; 1.2157x over previous
//
#include <hip/hip_runtime.h>

// Problem constants derived at launch from in_sizes:
// in[0]=x [B,TF,T], in[1]=gene_ids [T], in[2]=w_sub [TF,T], in[3]=b_sub [G],
// in[4]=edge_index [2,2E], in[5]=w_conv [1,2], in[6]=b_conv [2],
// in[7]=w_out [2G,3], in[8]=b_out [3]
// d_out = x_cat [B,G] ++ g [B,2G] ++ out [B,3]  (float32)
//
// SESSION LEDGER (best = this exact configuration, 723.0 us):
//  R1 fusion 8->5 dispatches: -17us (kept)
//  R2 coop mega-kernel: +398us (launch_bounds VGPR clamp + coop launch overhead)
//  R3 8-wide subnet: +19us (broke 16B/lane coalescing)
//  R4 XCD swizzle + edge-dedup scatter: null (w_sub L3 re-reads not on critical path)
//  R5 coop tail kernel: +152us (coop launch overhead ~150us in graph capture, 2nd confirmation)
// Floor arithmetic: ~550us harness re-poison fills + ~71us x-stream + ~45us glue/dispatch.

typedef float f32x4 __attribute__((ext_vector_type(4)));

// ---------------- Stage 1: per-gene subnet dot + segment scatter ----------------
// z[b,t] = sum_tf x[b,tf,t]*w_sub[tf,t];  acc[b, gene_ids[t]] += z[b,t]
// 4 cols/thread, 16B fully-coalesced lane loads; x streamed once (non-temporal)
// so w_sub (32x reuse) stays cache-resident.
__global__ void k_subnet(const float* __restrict__ x, const float* __restrict__ w_sub,
                         const int* __restrict__ gene_ids, float* __restrict__ acc,
                         int TF, int T, int G) {
    int t = (blockIdx.x * blockDim.x + threadIdx.x) * 4;
    int b = blockIdx.y;
    if (t >= T) return;
    const size_t xbase = (size_t)b * TF * T;
    if (t + 3 < T && (T % 4) == 0) {
        const f32x4* xp = (const f32x4*)(x + xbase + t);
        const f32x4* wp = (const f32x4*)(w_sub + t);
        const size_t strideV = (size_t)T / 4;
        f32x4 a = {0.f, 0.f, 0.f, 0.f};
        #pragma unroll 8
        for (int tf = 0; tf < TF; ++tf) {
            f32x4 xv = __builtin_nontemporal_load(xp + (size_t)tf * strideV);
            f32x4 wv = wp[(size_t)tf * strideV];
            a += xv * wv;
        }
        int4 gi = *(const int4*)(gene_ids + t);
        float* base = acc + (size_t)b * G;
        // merge adjacent columns belonging to the same gene before atomics
        float v = a.x; int cg = gi.x;
        if (gi.y == cg) v += a.y; else { atomicAdd(base + cg, v); cg = gi.y; v = a.y; }
        if (gi.z == cg) v += a.z; else { atomicAdd(base + cg, v); cg = gi.z; v = a.z; }
        if (gi.w == cg) v += a.w; else { atomicAdd(base + cg, v); cg = gi.w; v = a.w; }
        atomicAdd(base + cg, v);
    } else {
        // scalar tail (not taken for T % 4 == 0, kept for generality)
        for (int tt = t; tt < T && tt < t + 4; ++tt) {
            float a = 0.f;
            for (int tf = 0; tf < TF; ++tf)
                a += x[xbase + (size_t)tf * T + tt] * w_sub[(size_t)tf * T + tt];
            atomicAdd(acc + (size_t)b * G + gene_ids[tt], a);
        }
    }
}

// ---------------- Stage 2 (fused): x_cat = relu(acc+b_sub), deg count, out init ----
__global__ void k_xcatdeg(const float* __restrict__ acc, const float* __restrict__ b_sub,
                          float* __restrict__ xcat,
                          const int* __restrict__ ei, float* __restrict__ deg,
                          const float* __restrict__ b_out, float* __restrict__ out_fin,
                          int BG, int G, int E2, int B3) {
    int i = blockIdx.x * blockDim.x + threadIdx.x;
    if (i < BG) {
        int g = i % G;
        float v = acc[i] + b_sub[g];
        xcat[i] = v > 0.f ? v : 0.f;
    }
    if (i < E2) atomicAdd(&deg[ei[E2 + i]], 1.0f);
    if (i < B3) out_fin[i] = b_out[i % 3];   // bias-init so stage 4 can atomicAdd
}

// ---------------- Stage 3 (fused norm): s[b,dst] += xcat[b,src]*dinv[src]*dinv[dst] --
__global__ void k_scatter(const float* __restrict__ xcat, const int* __restrict__ ei,
                          const float* __restrict__ deg, float* __restrict__ s,
                          int G, int E2) {
    int e = blockIdx.x * blockDim.x + threadIdx.x;
    if (e >= E2) return;
    int b = blockIdx.y;
    int src = ei[e], dst = ei[E2 + e];
    float ds = deg[src], dd = deg[dst];
    float ns = (ds > 0.f) ? (1.0f / sqrtf(fmaxf(ds, 1.0f))) : 0.f;
    float nd = (dd > 0.f) ? (1.0f / sqrtf(fmaxf(dd, 1.0f))) : 0.f;
    atomicAdd(&s[(size_t)b * G + dst], xcat[(size_t)b * G + src] * (ns * nd));
}

// ---------------- Stage 4 (fused): g = relu(w_conv*s+b_conv)  AND  out = g@w_out+b_out
__global__ void k_gfinout(const float* __restrict__ s, const float* __restrict__ w_conv,
                          const float* __restrict__ b_conv, const float* __restrict__ w_out,
                          float* __restrict__ gout, float* __restrict__ out_fin, int G) {
    int n = blockIdx.x * blockDim.x + threadIdx.x;
    int b = blockIdx.y;
    float a0 = 0.f, a1 = 0.f, a2 = 0.f;
    if (n < G) {
        size_t i = (size_t)b * G + n;
        float sv = s[i];
        float g0 = sv * w_conv[0] + b_conv[0]; g0 = g0 > 0.f ? g0 : 0.f;
        float g1 = sv * w_conv[1] + b_conv[1]; g1 = g1 > 0.f ? g1 : 0.f;
        gout[2 * i + 0] = g0;                 // b*2G + 2n + f == 2*i + f
        gout[2 * i + 1] = g1;
        const float* w0 = w_out + (size_t)6 * n;  // rows 2n and 2n+1 of [2G,3]
        a0 = g0 * w0[0] + g1 * w0[3];
        a1 = g0 * w0[1] + g1 * w0[4];
        a2 = g0 * w0[2] + g1 * w0[5];
    }
    // 64-lane wave reduce, then cross-wave via LDS
    for (int off = 32; off > 0; off >>= 1) {
        a0 += __shfl_down(a0, off);
        a1 += __shfl_down(a1, off);
        a2 += __shfl_down(a2, off);
    }
    __shared__ float red[3][4];
    int lane = threadIdx.x & 63;
    int wid  = threadIdx.x >> 6;
    if (lane == 0) { red[0][wid] = a0; red[1][wid] = a1; red[2][wid] = a2; }
    __syncthreads();
    if (threadIdx.x == 0) {
        atomicAdd(&out_fin[b * 3 + 0], red[0][0] + red[0][1] + red[0][2] + red[0][3]);
        atomicAdd(&out_fin[b * 3 + 1], red[1][0] + red[1][1] + red[1][2] + red[1][3]);
        atomicAdd(&out_fin[b * 3 + 2], red[2][0] + red[2][1] + red[2][2] + red[2][3]);
    }
}

extern "C" void kernel_launch(void* const* d_in, const int* in_sizes, int n_in,
                              void* d_out, int out_size, void* d_ws, size_t ws_size,
                              hipStream_t stream) {
    const float* x        = (const float*)d_in[0];
    const int*   gene_ids = (const int*)d_in[1];
    const float* w_sub    = (const float*)d_in[2];
    const float* b_sub    = (const float*)d_in[3];
    const int*   ei       = (const int*)d_in[4];
    const float* w_conv   = (const float*)d_in[5];
    const float* b_conv   = (const float*)d_in[6];
    const float* w_out    = (const float*)d_in[7];
    const float* b_out    = (const float*)d_in[8];

    const int G  = in_sizes[3];
    const int T  = in_sizes[1];
    const int TF = in_sizes[2] / T;
    const int B  = in_sizes[0] / (TF * T);
    const int E2 = in_sizes[4] / 2;     // 2E
    const int BG = B * G;

    // workspace layout (floats): acc[BG] | deg/dinv[G] | s[BG]
    float* acc = (float*)d_ws;
    float* deg = acc + BG;
    float* s   = deg + G;
    hipMemsetAsync(d_ws, 0, (size_t)(BG + G + BG) * sizeof(float), stream);

    float* out_xcat = (float*)d_out;            // [B, G]
    float* out_g    = out_xcat + BG;            // [B, 2G]
    float* out_fin  = out_g + (size_t)2 * BG;   // [B, 3]

    // Stage 1
    {
        int tthreads = (T + 3) / 4;
        dim3 grid((tthreads + 255) / 256, B);
        k_subnet<<<grid, 256, 0, stream>>>(x, w_sub, gene_ids, acc, TF, T, G);
    }
    // Stage 2 (xcat + deg + out-bias-init)
    {
        int mx = BG > E2 ? BG : E2;
        int b3 = B * 3;
        if (mx < b3) mx = b3;
        k_xcatdeg<<<(mx + 255) / 256, 256, 0, stream>>>(acc, b_sub, out_xcat, ei, deg,
                                                        b_out, out_fin, BG, G, E2, b3);
    }
    // Stage 3 (scatter with on-the-fly GCN norm)
    {
        dim3 grid((E2 + 255) / 256, B);
        k_scatter<<<grid, 256, 0, stream>>>(out_xcat, ei, deg, s, G, E2);
    }
    // Stage 4 (g + final out, fused)
    {
        dim3 grid((G + 255) / 256, B);
        k_gfinout<<<grid, 256, 0, stream>>>(s, w_conv, b_conv, w_out, out_g, out_fin, G);
    }
}